// Round 2
// baseline (1868.481 us; speedup 1.0000x reference)
//
#include <hip/hip_runtime.h>
#include <hip/hip_bf16.h>

#define NN 100000
#define NE 600000
#define DD 128

// One wave per edge; lane handles dims 2*lane, 2*lane+1.
__global__ __launch_bounds__(256) void k_scatter(
    const float* __restrict__ node, const float* __restrict__ edge,
    const int* __restrict__ src, const int* __restrict__ dst,
    float* __restrict__ acc_o, float* __restrict__ acc_i,
    float* __restrict__ deg_dst, float* __restrict__ deg_src)
{
    int e = blockIdx.x * 4 + (threadIdx.x >> 6);
    int lane = threadIdx.x & 63;
    int s = src[e], t = dst[e];
    const float2* ns = (const float2*)(node + (size_t)s * DD);
    const float2* nt = (const float2*)(node + (size_t)t * DD);
    const float2* ee = (const float2*)(edge + (size_t)e * DD);
    float2 a = ns[lane]; float2 b = nt[lane]; float2 c = ee[lane];
    float* po = acc_o + (size_t)t * DD + 2 * lane;
    float* pi = acc_i + (size_t)s * DD + 2 * lane;
    unsafeAtomicAdd(po,     a.x - c.x);
    unsafeAtomicAdd(po + 1, a.y - c.y);
    unsafeAtomicAdd(pi,     b.x - c.x);
    unsafeAtomicAdd(pi + 1, b.y - c.y);
    if (lane == 0) {
        unsafeAtomicAdd(deg_dst + t, 1.0f);
        unsafeAtomicAdd(deg_src + s, 1.0f);
    }
}

// 32 nodes x 128 cols per block. Thread (l=tid&31, r=tid>>5): cols {l,l+32,l+64,l+96},
// nodes {4r..4r+3}. K staged in 4 chunks of 32. Writes h (f32, in-place over acc_o)
// and per-column sum / sumsq partials for BatchNorm.
__global__ __launch_bounds__(256) void k_gemm(
    const float* acc_o, const float* acc_i,
    const float* __restrict__ node,
    const float* __restrict__ deg_dst, const float* __restrict__ deg_src,
    const float* __restrict__ W0, const float* __restrict__ W1, const float* __restrict__ W2,
    const float* __restrict__ b0, const float* __restrict__ b1, const float* __restrict__ b2,
    float* h, float* __restrict__ col_sum, float* __restrict__ col_sumsq)
{
    __shared__ float s_w[3 * 128 * 34];   // weight chunk, stride 34 (bank-safe), 52224 B
    __shared__ float s_in[3 * 32 * 32];   // input chunk, 12288 B (reused for BN reduce)
    __shared__ float s_inv[64];           // 1/max(deg,1) for this tile

    const int tid = threadIdx.x;
    const int n0 = blockIdx.x * 32;
    const int l = tid & 31;
    const int r = tid >> 5;

    if (tid < 32) {
        s_inv[tid]      = 1.0f / fmaxf(deg_dst[n0 + tid], 1.0f);
        s_inv[32 + tid] = 1.0f / fmaxf(deg_src[n0 + tid], 1.0f);
    }

    float acc[4][4];
    #pragma unroll
    for (int a = 0; a < 4; a++)
        #pragma unroll
        for (int bb = 0; bb < 4; bb++) acc[a][bb] = 0.0f;

    for (int kc = 0; kc < 4; kc++) {
        const int k0 = kc * 32;
        __syncthreads();   // protect s_w/s_in from previous chunk (and s_inv on kc==0)

        // stage weights: 3 * 128 rows * 32 k
        #pragma unroll
        for (int m = 0; m < 3; m++) {
            const float* W = (m == 0) ? W0 : (m == 1) ? W1 : W2;
            #pragma unroll
            for (int i = 0; i < 16; i++) {
                int flat = i * 256 + tid;      // 0..4095
                int row  = flat >> 5;          // 0..127
                int kk   = flat & 31;
                s_w[(m * 128 + row) * 34 + kk] = W[row * 128 + k0 + kk];
            }
        }
        // stage inputs: ho, hi (scaled by inv-degree), x
        #pragma unroll
        for (int i = 0; i < 4; i++) {
            int n  = i * 8 + (tid >> 5);
            int kk = tid & 31;
            size_t g = (size_t)(n0 + n) * DD + k0 + kk;
            s_in[(0 * 32 + n) * 32 + kk] = acc_o[g] * s_inv[n];
            s_in[(1 * 32 + n) * 32 + kk] = acc_i[g] * s_inv[32 + n];
            s_in[(2 * 32 + n) * 32 + kk] = node[g];
        }
        __syncthreads();

        #pragma unroll
        for (int kk = 0; kk < 32; kk += 2) {
            float2 w[3][4];
            float2 x[3][4];
            #pragma unroll
            for (int m = 0; m < 3; m++) {
                #pragma unroll
                for (int jj = 0; jj < 4; jj++)
                    w[m][jj] = *(const float2*)&s_w[(m * 128 + l + 32 * jj) * 34 + kk];
                #pragma unroll
                for (int i = 0; i < 4; i++)
                    x[m][i] = *(const float2*)&s_in[(m * 32 + r * 4 + i) * 32 + kk];
            }
            #pragma unroll
            for (int jj = 0; jj < 4; jj++)
                #pragma unroll
                for (int i = 0; i < 4; i++) {
                    float t = acc[jj][i];
                    t = fmaf(w[0][jj].x, x[0][i].x, t);
                    t = fmaf(w[0][jj].y, x[0][i].y, t);
                    t = fmaf(w[1][jj].x, x[1][i].x, t);
                    t = fmaf(w[1][jj].y, x[1][i].y, t);
                    t = fmaf(w[2][jj].x, x[2][i].x, t);
                    t = fmaf(w[2][jj].y, x[2][i].y, t);
                    acc[jj][i] = t;
                }
        }
    }

    // epilogue: bias, /3, write h, per-column partial sums for BN
    const float third = 1.0f / 3.0f;
    float csum[4], csq[4];
    #pragma unroll
    for (int jj = 0; jj < 4; jj++) {
        int c = l + 32 * jj;
        float bsum = b0[c] + b1[c] + b2[c];
        csum[jj] = 0.0f; csq[jj] = 0.0f;
        #pragma unroll
        for (int i = 0; i < 4; i++) {
            int n = n0 + r * 4 + i;
            float v = (acc[jj][i] + bsum) * third;
            h[(size_t)n * DD + c] = v;
            csum[jj] += v;
            csq[jj] += v * v;
        }
    }
    __syncthreads();            // done reading s_in as inputs
    float* red = s_in;          // reuse: [8][128] sums + [8][128] sumsq
    #pragma unroll
    for (int jj = 0; jj < 4; jj++) {
        int c = l + 32 * jj;
        red[r * 128 + c]        = csum[jj];
        red[1024 + r * 128 + c] = csq[jj];
    }
    __syncthreads();
    if (tid < 128) {
        float s = 0.0f, q = 0.0f;
        #pragma unroll
        for (int rr = 0; rr < 8; rr++) {
            s += red[rr * 128 + tid];
            q += red[1024 + rr * 128 + tid];
        }
        unsafeAtomicAdd(col_sum + tid, s);
        unsafeAtomicAdd(col_sumsq + tid, q);
    }
}

__global__ void k_stats(const float* __restrict__ col_sum, const float* __restrict__ col_sumsq,
                        const float* __restrict__ gamma, const float* __restrict__ beta,
                        float* __restrict__ sc, float* __restrict__ bs)
{
    int t = threadIdx.x;
    float mu  = col_sum[t]   * (1.0f / NN);
    float var = col_sumsq[t] * (1.0f / NN) - mu * mu;
    var = fmaxf(var, 0.0f);
    float rs = rsqrtf(var + 1e-5f);
    float g = gamma[t];
    sc[t] = rs * g;
    bs[t] = beta[t] - mu * rs * g;
}

__global__ __launch_bounds__(256) void k_norm(const float* __restrict__ h,
        const float* __restrict__ sc, const float* __restrict__ bs,
        float* __restrict__ out)
{
    __shared__ float ssc[128], sbs[128];
    int tid = threadIdx.x;
    if (tid < 128) { ssc[tid] = sc[tid]; sbs[tid] = bs[tid]; }
    __syncthreads();
    size_t base = ((size_t)blockIdx.x * 256 + tid) * 4;
    float4 v = *(const float4*)(h + base);
    int j = (int)(base & 127);
    float4 o;
    o.x = fmaf(v.x, ssc[j],     sbs[j]);
    o.y = fmaf(v.y, ssc[j + 1], sbs[j + 1]);
    o.z = fmaf(v.z, ssc[j + 2], sbs[j + 2]);
    o.w = fmaf(v.w, ssc[j + 3], sbs[j + 3]);
    *(float4*)(out + base) = o;
}

extern "C" void kernel_launch(void* const* d_in, const int* in_sizes, int n_in,
                              void* d_out, int out_size, void* d_ws, size_t ws_size,
                              hipStream_t stream)
{
    const float* node  = (const float*)d_in[0];
    const float* edge  = (const float*)d_in[1];
    const float* W0    = (const float*)d_in[2];
    const float* b0    = (const float*)d_in[3];
    const float* W1    = (const float*)d_in[4];
    const float* b1    = (const float*)d_in[5];
    const float* W2    = (const float*)d_in[6];
    const float* b2    = (const float*)d_in[7];
    const float* gamma = (const float*)d_in[8];
    const float* beta  = (const float*)d_in[9];
    const int* src = (const int*)d_in[10];
    const int* dst = (const int*)d_in[11];
    float* out = (float*)d_out;

    const size_t NB = (size_t)NN * DD;
    float* acc_o     = (float*)d_ws;
    float* acc_i     = acc_o + NB;
    float* deg_dst   = acc_i + NB;
    float* deg_src   = deg_dst + NN;
    float* col_sum   = deg_src + NN;
    float* col_sumsq = col_sum + DD;
    float* sc        = col_sumsq + DD;
    float* bs        = sc + DD;
    float* h         = acc_o;   // reuse acc_o storage for h (per-block in-place safe)

    size_t zbytes = (2 * NB + 2 * (size_t)NN + 2 * (size_t)DD) * sizeof(float);
    hipMemsetAsync(d_ws, 0, zbytes, stream);

    k_scatter<<<NE / 4, 256, 0, stream>>>(node, edge, src, dst,
                                          acc_o, acc_i, deg_dst, deg_src);
    k_gemm<<<NN / 32, 256, 0, stream>>>(acc_o, acc_i, node, deg_dst, deg_src,
                                        W0, W1, W2, b0, b1, b2,
                                        h, col_sum, col_sumsq);
    k_stats<<<1, 128, 0, stream>>>(col_sum, col_sumsq, gamma, beta, sc, bs);
    k_norm<<<(NN * DD) / 1024, 256, 0, stream>>>(h, sc, bs, out);
}

// Round 3
// 1255.718 us; speedup vs baseline: 1.4880x; 1.4880x over previous
//
#include <hip/hip_runtime.h>
#include <hip/hip_bf16.h>

#define NN 100000
#define NE 600000
#define DD 128
#define NBLK 98   // ceil(NN/1024)

// ---------- counting-sort infrastructure ----------

__global__ __launch_bounds__(256) void k_hist(
    const int* __restrict__ src, const int* __restrict__ dst,
    int* __restrict__ cnt_o, int* __restrict__ cnt_i)
{
    int e = blockIdx.x * 256 + threadIdx.x;
    if (e < NE) {
        atomicAdd(&cnt_o[dst[e]], 1);
        atomicAdd(&cnt_i[src[e]], 1);
    }
}

// block (x=chunk of 1024, y=direction): chunk-local exclusive scan + chunk total
__global__ __launch_bounds__(256) void k_scanA(
    const int* __restrict__ cnt_o, const int* __restrict__ cnt_i,
    int* __restrict__ ptr_o, int* __restrict__ ptr_i, int* __restrict__ bsum)
{
    __shared__ int sh[256];
    const int* cnt = blockIdx.y ? cnt_i : cnt_o;
    int* ptr       = blockIdx.y ? ptr_i : ptr_o;
    int t = threadIdx.x;
    int base = blockIdx.x * 1024 + t * 4;
    int c[4];
    #pragma unroll
    for (int j = 0; j < 4; j++) c[j] = (base + j < NN) ? cnt[base + j] : 0;
    int s = c[0] + c[1] + c[2] + c[3];
    sh[t] = s;
    __syncthreads();
    for (int off = 1; off < 256; off <<= 1) {
        int v = (t >= off) ? sh[t - off] : 0;
        __syncthreads();
        sh[t] += v;
        __syncthreads();
    }
    int excl = sh[t] - s;
    int e0 = excl, e1 = e0 + c[0], e2 = e1 + c[1], e3 = e2 + c[2];
    if (base     < NN) ptr[base]     = e0;
    if (base + 1 < NN) ptr[base + 1] = e1;
    if (base + 2 < NN) ptr[base + 2] = e2;
    if (base + 3 < NN) ptr[base + 3] = e3;
    if (t == 255) bsum[blockIdx.y * 128 + blockIdx.x] = sh[255];
}

// scan the 98 chunk totals (per direction) to exclusive offsets, in place
__global__ __launch_bounds__(128) void k_scanB(int* __restrict__ bsum)
{
    __shared__ int sh[128];
    int t = threadIdx.x;
    int* b = bsum + blockIdx.y * 128;
    int v = (t < NBLK) ? b[t] : 0;
    sh[t] = v;
    __syncthreads();
    for (int off = 1; off < 128; off <<= 1) {
        int u = (t >= off) ? sh[t - off] : 0;
        __syncthreads();
        sh[t] += u;
        __syncthreads();
    }
    b[t] = sh[t] - v;   // exclusive
}

__global__ __launch_bounds__(256) void k_scanC(
    int* __restrict__ ptr_o, int* __restrict__ ptr_i, const int* __restrict__ bsum)
{
    int* ptr = blockIdx.y ? ptr_i : ptr_o;
    int off = bsum[blockIdx.y * 128 + blockIdx.x];
    int base = blockIdx.x * 1024 + threadIdx.x * 4;
    #pragma unroll
    for (int j = 0; j < 4; j++)
        if (base + j < NN) ptr[base + j] += off;
    if (blockIdx.x == 0 && threadIdx.x == 0) ptr[NN] = NE;
}

__global__ __launch_bounds__(256) void k_fill(
    const int* __restrict__ src, const int* __restrict__ dst,
    const int* __restrict__ ptr_o, const int* __restrict__ ptr_i,
    int* __restrict__ cur_o, int* __restrict__ cur_i,
    int* __restrict__ list_o, int* __restrict__ list_i)
{
    int e = blockIdx.x * 256 + threadIdx.x;
    if (e < NE) {
        int t = dst[e];
        int p = atomicAdd(&cur_o[t], 1);
        list_o[ptr_o[t] + p] = e;
        int s = src[e];
        int q = atomicAdd(&cur_i[s], 1);
        list_i[ptr_i[s] + q] = e;
    }
}

// ---------- gather: one wave per (node, direction); lane owns dims 2l,2l+1 ----------
__global__ __launch_bounds__(256) void k_gather(
    const float* __restrict__ node, const float* __restrict__ edge,
    const int* __restrict__ src, const int* __restrict__ dst,
    const int* __restrict__ ptr_o, const int* __restrict__ ptr_i,
    const int* __restrict__ list_o, const int* __restrict__ list_i,
    float* __restrict__ acc_o, float* __restrict__ acc_i)
{
    int gid = blockIdx.x * 4 + (threadIdx.x >> 6);   // [0, 2*NN)
    int lane = threadIdx.x & 63;
    int dirI = gid >= NN;
    int n = gid - (dirI ? NN : 0);
    const int* ptr  = dirI ? ptr_i  : ptr_o;
    const int* list = dirI ? list_i : list_o;
    const int* oth  = dirI ? dst    : src;
    float* acc      = dirI ? acc_i  : acc_o;

    int p0 = ptr[n], p1 = ptr[n + 1];
    float2 a = make_float2(0.0f, 0.0f);
    for (int j = p0; j < p1; j++) {
        int e = list[j];
        int u = oth[e];
        float2 x = ((const float2*)(node + (size_t)u * DD))[lane];
        float2 y = ((const float2*)(edge + (size_t)e * DD))[lane];
        a.x += x.x - y.x;
        a.y += x.y - y.y;
    }
    int d = p1 - p0;
    float inv = (d > 0) ? 1.0f / (float)d : 0.0f;
    a.x *= inv; a.y *= inv;
    ((float2*)(acc + (size_t)n * DD))[lane] = a;
}

// ---------- GEMM + BN partials (unchanged structure; inputs are already means) ----------
__global__ __launch_bounds__(256) void k_gemm(
    const float* acc_o, const float* acc_i,
    const float* __restrict__ node,
    const float* __restrict__ W0, const float* __restrict__ W1, const float* __restrict__ W2,
    const float* __restrict__ b0, const float* __restrict__ b1, const float* __restrict__ b2,
    float* h, float* __restrict__ col_sum, float* __restrict__ col_sumsq)
{
    __shared__ float s_w[3 * 128 * 34];   // weight chunk, stride 34 (bank-safe)
    __shared__ float s_in[3 * 32 * 32];   // input chunk (reused for BN reduce)

    const int tid = threadIdx.x;
    const int n0 = blockIdx.x * 32;
    const int l = tid & 31;
    const int r = tid >> 5;

    float acc[4][4];
    #pragma unroll
    for (int a = 0; a < 4; a++)
        #pragma unroll
        for (int bb = 0; bb < 4; bb++) acc[a][bb] = 0.0f;

    for (int kc = 0; kc < 4; kc++) {
        const int k0 = kc * 32;
        __syncthreads();

        #pragma unroll
        for (int m = 0; m < 3; m++) {
            const float* W = (m == 0) ? W0 : (m == 1) ? W1 : W2;
            #pragma unroll
            for (int i = 0; i < 16; i++) {
                int flat = i * 256 + tid;
                int row  = flat >> 5;
                int kk   = flat & 31;
                s_w[(m * 128 + row) * 34 + kk] = W[row * 128 + k0 + kk];
            }
        }
        #pragma unroll
        for (int i = 0; i < 4; i++) {
            int n  = i * 8 + (tid >> 5);
            int kk = tid & 31;
            size_t g = (size_t)(n0 + n) * DD + k0 + kk;
            s_in[(0 * 32 + n) * 32 + kk] = acc_o[g];
            s_in[(1 * 32 + n) * 32 + kk] = acc_i[g];
            s_in[(2 * 32 + n) * 32 + kk] = node[g];
        }
        __syncthreads();

        #pragma unroll
        for (int kk = 0; kk < 32; kk += 2) {
            float2 w[3][4];
            float2 x[3][4];
            #pragma unroll
            for (int m = 0; m < 3; m++) {
                #pragma unroll
                for (int jj = 0; jj < 4; jj++)
                    w[m][jj] = *(const float2*)&s_w[(m * 128 + l + 32 * jj) * 34 + kk];
                #pragma unroll
                for (int i = 0; i < 4; i++)
                    x[m][i] = *(const float2*)&s_in[(m * 32 + r * 4 + i) * 32 + kk];
            }
            #pragma unroll
            for (int jj = 0; jj < 4; jj++)
                #pragma unroll
                for (int i = 0; i < 4; i++) {
                    float t = acc[jj][i];
                    t = fmaf(w[0][jj].x, x[0][i].x, t);
                    t = fmaf(w[0][jj].y, x[0][i].y, t);
                    t = fmaf(w[1][jj].x, x[1][i].x, t);
                    t = fmaf(w[1][jj].y, x[1][i].y, t);
                    t = fmaf(w[2][jj].x, x[2][i].x, t);
                    t = fmaf(w[2][jj].y, x[2][i].y, t);
                    acc[jj][i] = t;
                }
        }
    }

    const float third = 1.0f / 3.0f;
    float csum[4], csq[4];
    #pragma unroll
    for (int jj = 0; jj < 4; jj++) {
        int c = l + 32 * jj;
        float bsum = b0[c] + b1[c] + b2[c];
        csum[jj] = 0.0f; csq[jj] = 0.0f;
        #pragma unroll
        for (int i = 0; i < 4; i++) {
            int n = n0 + r * 4 + i;
            float v = (acc[jj][i] + bsum) * third;
            h[(size_t)n * DD + c] = v;
            csum[jj] += v;
            csq[jj] += v * v;
        }
    }
    __syncthreads();
    float* red = s_in;
    #pragma unroll
    for (int jj = 0; jj < 4; jj++) {
        int c = l + 32 * jj;
        red[r * 128 + c]        = csum[jj];
        red[1024 + r * 128 + c] = csq[jj];
    }
    __syncthreads();
    if (tid < 128) {
        float s = 0.0f, q = 0.0f;
        #pragma unroll
        for (int rr = 0; rr < 8; rr++) {
            s += red[rr * 128 + tid];
            q += red[1024 + rr * 128 + tid];
        }
        unsafeAtomicAdd(col_sum + tid, s);
        unsafeAtomicAdd(col_sumsq + tid, q);
    }
}

__global__ void k_stats(const float* __restrict__ col_sum, const float* __restrict__ col_sumsq,
                        const float* __restrict__ gamma, const float* __restrict__ beta,
                        float* __restrict__ sc, float* __restrict__ bs)
{
    int t = threadIdx.x;
    float mu  = col_sum[t]   * (1.0f / NN);
    float var = col_sumsq[t] * (1.0f / NN) - mu * mu;
    var = fmaxf(var, 0.0f);
    float rs = rsqrtf(var + 1e-5f);
    float g = gamma[t];
    sc[t] = rs * g;
    bs[t] = beta[t] - mu * rs * g;
}

__global__ __launch_bounds__(256) void k_norm(const float* __restrict__ h,
        const float* __restrict__ sc, const float* __restrict__ bs,
        float* __restrict__ out)
{
    __shared__ float ssc[128], sbs[128];
    int tid = threadIdx.x;
    if (tid < 128) { ssc[tid] = sc[tid]; sbs[tid] = bs[tid]; }
    __syncthreads();
    size_t base = ((size_t)blockIdx.x * 256 + tid) * 4;
    float4 v = *(const float4*)(h + base);
    int j = (int)(base & 127);
    float4 o;
    o.x = fmaf(v.x, ssc[j],     sbs[j]);
    o.y = fmaf(v.y, ssc[j + 1], sbs[j + 1]);
    o.z = fmaf(v.z, ssc[j + 2], sbs[j + 2]);
    o.w = fmaf(v.w, ssc[j + 3], sbs[j + 3]);
    *(float4*)(out + base) = o;
}

extern "C" void kernel_launch(void* const* d_in, const int* in_sizes, int n_in,
                              void* d_out, int out_size, void* d_ws, size_t ws_size,
                              hipStream_t stream)
{
    const float* node  = (const float*)d_in[0];
    const float* edge  = (const float*)d_in[1];
    const float* W0    = (const float*)d_in[2];
    const float* b0    = (const float*)d_in[3];
    const float* W1    = (const float*)d_in[4];
    const float* b1    = (const float*)d_in[5];
    const float* W2    = (const float*)d_in[6];
    const float* b2    = (const float*)d_in[7];
    const float* gamma = (const float*)d_in[8];
    const float* beta  = (const float*)d_in[9];
    const int* src = (const int*)d_in[10];
    const int* dst = (const int*)d_in[11];
    float* out = (float*)d_out;

    const size_t NB = (size_t)NN * DD;
    float* acc_o = (float*)d_ws;           // NB floats
    float* acc_i = acc_o + NB;             // NB floats
    // ---- zeroed region starts here (16B-aligned: 2*NB*4 bytes) ----
    int* cnt_o = (int*)(acc_i + NB);       // NN
    int* cnt_i = cnt_o + NN;               // NN
    int* cur_o = cnt_i + NN;               // NN
    int* cur_i = cur_o + NN;               // NN
    float* col_sum   = (float*)(cur_i + NN);   // 128
    float* col_sumsq = col_sum + DD;           // 128
    // ---- zeroed region ends: (4*NN + 256) * 4 bytes ----
    int* ptr_o = (int*)(col_sumsq + DD);   // NN+1
    int* ptr_i = ptr_o + (NN + 1);         // NN+1
    int* bsum  = ptr_i + (NN + 1);         // 2*128
    int* list_o = bsum + 256;              // NE
    int* list_i = list_o + NE;             // NE
    float* sc = (float*)(list_i + NE);     // 128
    float* bs = sc + DD;                   // 128
    float* h  = acc_o;                     // reuse acc_o for h (per-block in-place safe)

    size_t zbytes = (size_t)(4 * NN + 2 * DD) * sizeof(int);
    hipMemsetAsync(cnt_o, 0, zbytes, stream);

    int egrid = (NE + 255) / 256;
    k_hist <<<egrid, 256, 0, stream>>>(src, dst, cnt_o, cnt_i);
    k_scanA<<<dim3(NBLK, 2), 256, 0, stream>>>(cnt_o, cnt_i, ptr_o, ptr_i, bsum);
    k_scanB<<<dim3(1, 2), 128, 0, stream>>>(bsum);
    k_scanC<<<dim3(NBLK, 2), 256, 0, stream>>>(ptr_o, ptr_i, bsum);
    k_fill <<<egrid, 256, 0, stream>>>(src, dst, ptr_o, ptr_i, cur_o, cur_i, list_o, list_i);
    k_gather<<<(2 * NN) / 4, 256, 0, stream>>>(node, edge, src, dst,
                                               ptr_o, ptr_i, list_o, list_i, acc_o, acc_i);
    k_gemm<<<NN / 32, 256, 0, stream>>>(acc_o, acc_i, node,
                                        W0, W1, W2, b0, b1, b2,
                                        h, col_sum, col_sumsq);
    k_stats<<<1, 128, 0, stream>>>(col_sum, col_sumsq, gamma, beta, sc, bs);
    k_norm<<<(NN * DD) / 1024, 256, 0, stream>>>(h, sc, bs, out);
}

// Round 4
// 942.572 us; speedup vs baseline: 1.9823x; 1.3322x over previous
//
#include <hip/hip_runtime.h>
#include <hip/hip_bf16.h>

#define NN 100000
#define NE 600000
#define DD 128
#define NBLK 98   // ceil(NN/1024)

typedef __attribute__((ext_vector_type(8))) short short8_t;
typedef __attribute__((ext_vector_type(4))) float float4_t;

__device__ __forceinline__ unsigned short f2bf(float f) {
    union { float f; unsigned int i; } v; v.f = f;
    unsigned int r = v.i + 0x7fffu + ((v.i >> 16) & 1u);
    return (unsigned short)(r >> 16);
}

// ---------- counting-sort infrastructure ----------

__global__ __launch_bounds__(256) void k_hist(
    const int* __restrict__ src, const int* __restrict__ dst,
    int* __restrict__ cnt_o, int* __restrict__ cnt_i)
{
    int e = blockIdx.x * 256 + threadIdx.x;
    if (e < NE) {
        atomicAdd(&cnt_o[dst[e]], 1);
        atomicAdd(&cnt_i[src[e]], 1);
    }
}

__global__ __launch_bounds__(256) void k_scanA(
    const int* __restrict__ cnt_o, const int* __restrict__ cnt_i,
    int* __restrict__ ptr_o, int* __restrict__ ptr_i, int* __restrict__ bsum)
{
    __shared__ int sh[256];
    const int* cnt = blockIdx.y ? cnt_i : cnt_o;
    int* ptr       = blockIdx.y ? ptr_i : ptr_o;
    int t = threadIdx.x;
    int base = blockIdx.x * 1024 + t * 4;
    int c[4];
    #pragma unroll
    for (int j = 0; j < 4; j++) c[j] = (base + j < NN) ? cnt[base + j] : 0;
    int s = c[0] + c[1] + c[2] + c[3];
    sh[t] = s;
    __syncthreads();
    for (int off = 1; off < 256; off <<= 1) {
        int v = (t >= off) ? sh[t - off] : 0;
        __syncthreads();
        sh[t] += v;
        __syncthreads();
    }
    int excl = sh[t] - s;
    int e0 = excl, e1 = e0 + c[0], e2 = e1 + c[1], e3 = e2 + c[2];
    if (base     < NN) ptr[base]     = e0;
    if (base + 1 < NN) ptr[base + 1] = e1;
    if (base + 2 < NN) ptr[base + 2] = e2;
    if (base + 3 < NN) ptr[base + 3] = e3;
    if (t == 255) bsum[blockIdx.y * 128 + blockIdx.x] = sh[255];
}

__global__ __launch_bounds__(128) void k_scanB(int* __restrict__ bsum)
{
    __shared__ int sh[128];
    int t = threadIdx.x;
    int* b = bsum + blockIdx.y * 128;
    int v = (t < NBLK) ? b[t] : 0;
    sh[t] = v;
    __syncthreads();
    for (int off = 1; off < 128; off <<= 1) {
        int u = (t >= off) ? sh[t - off] : 0;
        __syncthreads();
        sh[t] += u;
        __syncthreads();
    }
    b[t] = sh[t] - v;   // exclusive
}

__global__ __launch_bounds__(256) void k_scanC(
    int* __restrict__ ptr_o, int* __restrict__ ptr_i, const int* __restrict__ bsum)
{
    int* ptr = blockIdx.y ? ptr_i : ptr_o;
    int off = bsum[blockIdx.y * 128 + blockIdx.x];
    int base = blockIdx.x * 1024 + threadIdx.x * 4;
    #pragma unroll
    for (int j = 0; j < 4; j++)
        if (base + j < NN) ptr[base + j] += off;
    if (blockIdx.x == 0 && threadIdx.x == 0) ptr[NN] = NE;
}

__global__ __launch_bounds__(256) void k_fill(
    const int* __restrict__ src, const int* __restrict__ dst,
    const int* __restrict__ ptr_o, const int* __restrict__ ptr_i,
    int* __restrict__ cur_o, int* __restrict__ cur_i,
    int* __restrict__ list_o, int* __restrict__ list_i)
{
    int e = blockIdx.x * 256 + threadIdx.x;
    if (e < NE) {
        int t = dst[e];
        int p = atomicAdd(&cur_o[t], 1);
        list_o[ptr_o[t] + p] = e;
        int s = src[e];
        int q = atomicAdd(&cur_i[s], 1);
        list_i[ptr_i[s] + q] = e;
    }
}

// ---------- gather: one wave per (node, direction); lane owns dims 2l,2l+1 ----------
__global__ __launch_bounds__(256) void k_gather(
    const float* __restrict__ node, const float* __restrict__ edge,
    const int* __restrict__ src, const int* __restrict__ dst,
    const int* __restrict__ ptr_o, const int* __restrict__ ptr_i,
    const int* __restrict__ list_o, const int* __restrict__ list_i,
    float* __restrict__ acc_o, float* __restrict__ acc_i)
{
    int gid = blockIdx.x * 4 + (threadIdx.x >> 6);   // [0, 2*NN)
    int lane = threadIdx.x & 63;
    int dirI = gid >= NN;
    int n = gid - (dirI ? NN : 0);
    const int* ptr  = dirI ? ptr_i  : ptr_o;
    const int* list = dirI ? list_i : list_o;
    const int* oth  = dirI ? dst    : src;
    float* acc      = dirI ? acc_i  : acc_o;

    int p0 = ptr[n], p1 = ptr[n + 1];
    float2 a = make_float2(0.0f, 0.0f);
    for (int j = p0; j < p1; j++) {
        int e = list[j];
        int u = oth[e];
        float2 x = ((const float2*)(node + (size_t)u * DD))[lane];
        float2 y = ((const float2*)(edge + (size_t)e * DD))[lane];
        a.x += x.x - y.x;
        a.y += x.y - y.y;
    }
    int d = p1 - p0;
    float inv = (d > 0) ? 1.0f / (float)d : 0.0f;
    a.x *= inv; a.y *= inv;
    ((float2*)(acc + (size_t)n * DD))[lane] = a;
}

// ---------- MFMA GEMM: 32 rows x 128 cols per block, K=384 (3 x 128 concat) ----------
// Wave w: cols [32w, 32w+32), 2x2 tiles of 16x16 via mfma_f32_16x16x32_bf16.
// Inputs staged f32 -> bf16 into LDS (stride 40 shorts = 80 B: 16B-aligned frags,
// <=2-way bank aliasing). Writes h (f32, overlays acc_o rows of this block only)
// plus per-column BN partials.
__global__ __launch_bounds__(256) void k_gemm(
    const float* acc_o, const float* acc_i,
    const float* __restrict__ node,
    const float* __restrict__ W0, const float* __restrict__ W1, const float* __restrict__ W2,
    const float* __restrict__ b0, const float* __restrict__ b1, const float* __restrict__ b2,
    float* h, float* __restrict__ col_sum, float* __restrict__ col_sumsq)
{
    __shared__ unsigned short s_a[32 * 40];    // 2560 B
    __shared__ unsigned short s_b[128 * 40];   // 10240 B
    __shared__ float s_red[2 * 4 * 128];       // 4096 B

    const int tid = threadIdx.x;
    const int n0 = blockIdx.x * 32;
    const int w  = tid >> 6;
    const int l  = tid & 63;
    const int q  = l >> 4;
    const int li = l & 15;

    float4_t acc[2][2];
    #pragma unroll
    for (int i = 0; i < 2; i++)
        #pragma unroll
        for (int j = 0; j < 2; j++) acc[i][j] = (float4_t){0.f, 0.f, 0.f, 0.f};

    const int srow = tid >> 3;      // 0..31
    const int skq  = tid & 7;       // float4 slot 0..7

    for (int kc = 0; kc < 12; kc++) {
        const int m  = kc >> 2;
        const int k0 = (kc & 3) * 32;
        const float* X = (m == 0) ? acc_o : (m == 1) ? acc_i : node;
        const float* W = (m == 0) ? W0    : (m == 1) ? W1    : W2;

        __syncthreads();   // frag reads of previous chunk complete

        // stage A: 32 rows x 32 k
        {
            float4 v = *(const float4*)&X[(size_t)(n0 + srow) * DD + k0 + 4 * skq];
            ushort4 o = { f2bf(v.x), f2bf(v.y), f2bf(v.z), f2bf(v.w) };
            *(ushort4*)&s_a[srow * 40 + 4 * skq] = o;
        }
        // stage B: 128 c-rows x 32 k
        #pragma unroll
        for (int p = 0; p < 4; p++) {
            int row = 32 * p + srow;
            float4 v = *(const float4*)&W[row * DD + k0 + 4 * skq];
            ushort4 o = { f2bf(v.x), f2bf(v.y), f2bf(v.z), f2bf(v.w) };
            *(ushort4*)&s_b[row * 40 + 4 * skq] = o;
        }
        __syncthreads();

        short8_t af0 = *(const short8_t*)&s_a[li * 40 + q * 8];
        short8_t af1 = *(const short8_t*)&s_a[(16 + li) * 40 + q * 8];
        short8_t bf0 = *(const short8_t*)&s_b[(32 * w + li) * 40 + q * 8];
        short8_t bf1 = *(const short8_t*)&s_b[(32 * w + 16 + li) * 40 + q * 8];

        acc[0][0] = __builtin_amdgcn_mfma_f32_16x16x32_bf16(af0, bf0, acc[0][0], 0, 0, 0);
        acc[0][1] = __builtin_amdgcn_mfma_f32_16x16x32_bf16(af0, bf1, acc[0][1], 0, 0, 0);
        acc[1][0] = __builtin_amdgcn_mfma_f32_16x16x32_bf16(af1, bf0, acc[1][0], 0, 0, 0);
        acc[1][1] = __builtin_amdgcn_mfma_f32_16x16x32_bf16(af1, bf1, acc[1][1], 0, 0, 0);
    }

    // epilogue: bias, /3, store h, BN partials
    // C/D layout: col = lane&15 (within 16-tile), row = (lane>>4)*4 + reg
    const float third = 1.0f / 3.0f;
    #pragma unroll
    for (int j = 0; j < 2; j++) {
        int c = 32 * w + 16 * j + li;
        float bsum = b0[c] + b1[c] + b2[c];
        float s = 0.f, sq = 0.f;
        #pragma unroll
        for (int i = 0; i < 2; i++)
            #pragma unroll
            for (int reg = 0; reg < 4; reg++) {
                int r = n0 + 16 * i + q * 4 + reg;
                float v = (acc[i][j][reg] + bsum) * third;
                h[(size_t)r * DD + c] = v;
                s += v; sq += v * v;
            }
        s_red[q * 128 + c]       = s;
        s_red[512 + q * 128 + c] = sq;
    }
    __syncthreads();
    if (tid < 128) {
        float s = 0.f, sq = 0.f;
        #pragma unroll
        for (int r4 = 0; r4 < 4; r4++) {
            s  += s_red[r4 * 128 + tid];
            sq += s_red[512 + r4 * 128 + tid];
        }
        unsafeAtomicAdd(col_sum + tid, s);
        unsafeAtomicAdd(col_sumsq + tid, sq);
    }
}

__global__ void k_stats(const float* __restrict__ col_sum, const float* __restrict__ col_sumsq,
                        const float* __restrict__ gamma, const float* __restrict__ beta,
                        float* __restrict__ sc, float* __restrict__ bs)
{
    int t = threadIdx.x;
    float mu  = col_sum[t]   * (1.0f / NN);
    float var = col_sumsq[t] * (1.0f / NN) - mu * mu;
    var = fmaxf(var, 0.0f);
    float rs = rsqrtf(var + 1e-5f);
    float g = gamma[t];
    sc[t] = rs * g;
    bs[t] = beta[t] - mu * rs * g;
}

__global__ __launch_bounds__(256) void k_norm(const float* __restrict__ h,
        const float* __restrict__ sc, const float* __restrict__ bs,
        float* __restrict__ out)
{
    __shared__ float ssc[128], sbs[128];
    int tid = threadIdx.x;
    if (tid < 128) { ssc[tid] = sc[tid]; sbs[tid] = bs[tid]; }
    __syncthreads();
    size_t base = ((size_t)blockIdx.x * 256 + tid) * 4;
    float4 v = *(const float4*)(h + base);
    int j = (int)(base & 127);
    float4 o;
    o.x = fmaf(v.x, ssc[j],     sbs[j]);
    o.y = fmaf(v.y, ssc[j + 1], sbs[j + 1]);
    o.z = fmaf(v.z, ssc[j + 2], sbs[j + 2]);
    o.w = fmaf(v.w, ssc[j + 3], sbs[j + 3]);
    *(float4*)(out + base) = o;
}

extern "C" void kernel_launch(void* const* d_in, const int* in_sizes, int n_in,
                              void* d_out, int out_size, void* d_ws, size_t ws_size,
                              hipStream_t stream)
{
    const float* node  = (const float*)d_in[0];
    const float* edge  = (const float*)d_in[1];
    const float* W0    = (const float*)d_in[2];
    const float* b0    = (const float*)d_in[3];
    const float* W1    = (const float*)d_in[4];
    const float* b1    = (const float*)d_in[5];
    const float* W2    = (const float*)d_in[6];
    const float* b2    = (const float*)d_in[7];
    const float* gamma = (const float*)d_in[8];
    const float* beta  = (const float*)d_in[9];
    const int* src = (const int*)d_in[10];
    const int* dst = (const int*)d_in[11];
    float* out = (float*)d_out;

    const size_t NB = (size_t)NN * DD;
    float* acc_o = (float*)d_ws;           // NB floats
    float* acc_i = acc_o + NB;             // NB floats
    // ---- zeroed region ----
    int* cnt_o = (int*)(acc_i + NB);       // NN
    int* cnt_i = cnt_o + NN;               // NN
    int* cur_o = cnt_i + NN;               // NN
    int* cur_i = cur_o + NN;               // NN
    float* col_sum   = (float*)(cur_i + NN);   // 128
    float* col_sumsq = col_sum + DD;           // 128
    // ---- end zeroed region ----
    int* ptr_o = (int*)(col_sumsq + DD);   // NN+1
    int* ptr_i = ptr_o + (NN + 1);         // NN+1
    int* bsum  = ptr_i + (NN + 1);         // 2*128
    int* list_o = bsum + 256;              // NE
    int* list_i = list_o + NE;             // NE
    float* sc = (float*)(list_i + NE);     // 128
    float* bs = sc + DD;                   // 128
    float* h  = acc_o;                     // reuse acc_o for h (per-block in-place safe)

    size_t zbytes = (size_t)(4 * NN + 2 * DD) * sizeof(int);
    hipMemsetAsync(cnt_o, 0, zbytes, stream);

    int egrid = (NE + 255) / 256;
    k_hist <<<egrid, 256, 0, stream>>>(src, dst, cnt_o, cnt_i);
    k_scanA<<<dim3(NBLK, 2), 256, 0, stream>>>(cnt_o, cnt_i, ptr_o, ptr_i, bsum);
    k_scanB<<<dim3(1, 2), 128, 0, stream>>>(bsum);
    k_scanC<<<dim3(NBLK, 2), 256, 0, stream>>>(ptr_o, ptr_i, bsum);
    k_fill <<<egrid, 256, 0, stream>>>(src, dst, ptr_o, ptr_i, cur_o, cur_i, list_o, list_i);
    k_gather<<<(2 * NN) / 4, 256, 0, stream>>>(node, edge, src, dst,
                                               ptr_o, ptr_i, list_o, list_i, acc_o, acc_i);
    k_gemm<<<NN / 32, 256, 0, stream>>>(acc_o, acc_i, node,
                                        W0, W1, W2, b0, b1, b2,
                                        h, col_sum, col_sumsq);
    k_stats<<<1, 128, 0, stream>>>(col_sum, col_sumsq, gamma, beta, sc, bs);
    k_norm<<<(NN * DD) / 1024, 256, 0, stream>>>(h, sc, bs, out);
}